// Round 4
// baseline (957.039 us; speedup 1.0000x reference)
//
#include <hip/hip_runtime.h>
#include <hip/hip_bf16.h>

// ---------------------------------------------------------------------------
// ToMe16 token merge (6 rounds, fp32, numpy-exact decision order) +
// bf16-MFMA 2-layer MLP.  MI355X gfx950.
// ---------------------------------------------------------------------------

typedef __attribute__((ext_vector_type(8))) short bf16x8;
typedef __attribute__((ext_vector_type(4))) float f32x4;

// metric = mean over 16 heads of x (p,16,64), then L2-normalize rows.
__global__ __launch_bounds__(256) void metric_kernel(const float* __restrict__ x,
                                                     float* __restrict__ mnorm, int p)
{
    int row  = blockIdx.x * 4 + (threadIdx.x >> 6);
    int lane = threadIdx.x & 63;
    if (row >= p) return;
    const float* xr = x + (size_t)row * 1024;
    float m = 0.f;
#pragma unroll
    for (int h = 0; h < 16; ++h) m += xr[h * 64 + lane];
    m *= 0.0625f;
    float s = m * m;
#pragma unroll
    for (int off = 32; off > 0; off >>= 1) s += __shfl_xor(s, off, 64);
    mnorm[(size_t)row * 64 + lane] = m / sqrtf(s);
}

// scores[i][j] = dot(a_i, b_j), d=0..63 scalar fmaf ascending (bit-identical
// chain to the proven kernel => same argmax decisions).
// Tile: i 64 x j 128. As [d][i] pad 68; Bs [d][j] pad 132 (mult of 4 for
// float4 alignment; mod 32 = 4 keeps read groups conflict-free).
// Per thread: 4 i x 8 j (two float4 groups at tx*4 and 64+tx*4).
__global__ __launch_bounds__(256) void scores_kernel(const float* __restrict__ metric,
                                                     float* __restrict__ pmax,
                                                     int* __restrict__ pidx, int P2)
{
    __shared__ float As[64 * 68];
    __shared__ float Bs[64 * 132];
    const int t = threadIdx.x;
    const int i0 = blockIdx.x * 64, j0 = blockIdx.y * 128;

#pragma unroll
    for (int u = 0; u < 16; ++u) {
        int idx = u * 256 + t;
        int d = idx & 63, i = idx >> 6;
        int gi = i0 + i;
        As[d * 68 + i] = (gi < P2) ? metric[(size_t)(2 * gi) * 64 + d] : 0.f;
    }
#pragma unroll
    for (int u = 0; u < 32; ++u) {
        int idx = u * 256 + t;
        int d = idx & 63, j = idx >> 6;
        int gj = j0 + j;
        Bs[d * 132 + j] = (gj < P2) ? metric[(size_t)(2 * gj + 1) * 64 + d] : 0.f;
    }
    __syncthreads();

    const int tx = t & 15, ty = t >> 4;
    float acc[4][8];
#pragma unroll
    for (int u = 0; u < 4; ++u)
#pragma unroll
        for (int v = 0; v < 8; ++v) acc[u][v] = 0.f;

    for (int d = 0; d < 64; ++d) {
        float4 av = *reinterpret_cast<const float4*>(&As[d * 68 + ty * 4]);
        float4 b0 = *reinterpret_cast<const float4*>(&Bs[d * 132 + tx * 4]);
        float4 b1 = *reinterpret_cast<const float4*>(&Bs[d * 132 + 64 + tx * 4]);
        float a_[4] = {av.x, av.y, av.z, av.w};
        float b_[8] = {b0.x, b0.y, b0.z, b0.w, b1.x, b1.y, b1.z, b1.w};
#pragma unroll
        for (int u = 0; u < 4; ++u)
#pragma unroll
            for (int v = 0; v < 8; ++v)
                acc[u][v] = fmaf(a_[u], b_[v], acc[u][v]);
    }

#pragma unroll
    for (int u = 0; u < 4; ++u) {
        float best = -3.0e38f; int bj = 0x7fffffff;
        // ascending j within thread: group0 (tx*4+v), then group1 (64+tx*4+v)
#pragma unroll
        for (int v = 0; v < 4; ++v) {
            int j = j0 + tx * 4 + v;
            if (j < P2 && acc[u][v] > best) { best = acc[u][v]; bj = j; }
        }
#pragma unroll
        for (int v = 0; v < 4; ++v) {
            int j = j0 + 64 + tx * 4 + v;
            if (j < P2 && acc[u][4 + v] > best) { best = acc[u][4 + v]; bj = j; }
        }
#pragma unroll
        for (int off = 1; off < 16; off <<= 1) {
            float ob = __shfl_xor(best, off, 64);
            int   oj = __shfl_xor(bj,   off, 64);
            if (ob > best || (ob == best && oj < bj)) { best = ob; bj = oj; }
        }
        if (tx == 0) {
            int gi = i0 + ty * 4 + u;
            if (gi < P2) {
                pmax[(size_t)blockIdx.y * P2 + gi] = best;
                pidx[(size_t)blockIdx.y * P2 + gi] = bj;
            }
        }
    }
}

__global__ __launch_bounds__(256) void reduce_kernel(const float* __restrict__ pmax,
                                                     const int* __restrict__ pidx,
                                                     float* __restrict__ nmax,
                                                     int* __restrict__ nidx,
                                                     int P2, int JS)
{
    int i = blockIdx.x * 256 + threadIdx.x;
    if (i >= P2) return;
    float best = -3.3e38f; int bj = 0;
    for (int js = 0; js < JS; ++js) {
        float v = pmax[(size_t)js * P2 + i];
        if (v > best) { best = v; bj = pidx[(size_t)js * P2 + i]; }
    }
    nmax[i] = best; nidx[i] = bj;
}

// Rounds 1-5 (r == p/2). 8 dst-j per block; one nidx scan serves all 8.
// Duplicate accumulation ordered by (node_max desc, idx asc) == np.add.at.
#define JPB 8
__global__ __launch_bounds__(256) void merge_kernel(const float* __restrict__ x,
                                                    const float* __restrict__ size_in,
                                                    const int* __restrict__ nidx,
                                                    const float* __restrict__ nmax,
                                                    float* __restrict__ xout,
                                                    float* __restrict__ size_out, int P2)
{
    int j0 = blockIdx.x * JPB;
    __shared__ int   list[JPB][128];
    __shared__ int   cnt[JPB];
    __shared__ float ns_s[JPB];
    const int t = threadIdx.x;
    if (t < JPB) cnt[t] = 0;
    __syncthreads();
    for (int i = t; i < P2; i += 256) {
        int jj = nidx[i] - j0;
        if (jj >= 0 && jj < JPB) {
            int p = atomicAdd(&cnt[jj], 1);
            if (p < 128) list[jj][p] = i;
        }
    }
    __syncthreads();
    if (t < JPB) {
        int jj = t, j = j0 + jj;
        int total = cnt[jj];
        float ns = size_in ? size_in[2 * j + 1] : 1.0f;
        if (total <= 128) {
            for (int u = 1; u < total; ++u) {             // (nmax desc, idx asc)
                int v = list[jj][u]; float kv = nmax[v]; int w = u - 1;
                while (w >= 0) {
                    int lw = list[jj][w]; float kw = nmax[lw];
                    if (kw < kv || (kw == kv && lw > v)) { list[jj][w + 1] = lw; --w; }
                    else break;
                }
                list[jj][w + 1] = v;
            }
            for (int u = 0; u < total; ++u)
                ns += size_in ? size_in[2 * list[jj][u]] : 1.0f;
        } else {
            for (int i = 0; i < P2; ++i)
                if (nidx[i] == j) ns += size_in ? size_in[2 * i] : 1.0f;
        }
        ns_s[jj] = ns;
        size_out[j] = ns;
    }
    __syncthreads();
    for (int jj = 0; jj < JPB; ++jj) {
        int j = j0 + jj;
        int total = cnt[jj];
        bool over = (total > 128);
        float ns = ns_s[jj];
        float sodd = size_in ? size_in[2 * j + 1] : 1.0f;
        for (int c = t; c < 1024; c += 256) {
            float acc = x[(size_t)(2 * j + 1) * 1024 + c] * sodd;
            if (!over) {
                for (int u = 0; u < total; ++u) {
                    int i2 = list[jj][u];
                    float si = size_in ? size_in[2 * i2] : 1.0f;
                    acc += x[(size_t)(2 * i2) * 1024 + c] * si;
                }
            } else {
                for (int i2 = 0; i2 < P2; ++i2) {
                    if (nidx[i2] == j) {
                        float si = size_in ? size_in[2 * i2] : 1.0f;
                        acc += x[(size_t)(2 * i2) * 1024 + c] * si;
                    }
                }
            }
            xout[(size_t)j * 1024 + c] = acc / ns;
        }
    }
}

// Round 6 helpers (stable descending argsort, unm gather, dst scatter).
__global__ __launch_bounds__(512) void rank_kernel(const float* __restrict__ nmax,
                                                   int* __restrict__ edgeidx, int n)
{
    int i = threadIdx.x;
    if (i >= n) return;
    float v = nmax[i];
    int r = 0;
    for (int k = 0; k < n; ++k) {
        float u = nmax[k];
        if (u > v || (u == v && k < i)) ++r;
    }
    edgeidx[r] = i;
}

__global__ __launch_bounds__(256) void unm_kernel(const float* __restrict__ x,
                                                  const float* __restrict__ size_in,
                                                  const int* __restrict__ edgeidx,
                                                  float* __restrict__ xout, int r)
{
    int tb = blockIdx.x;
    int i = edgeidx[r + tb];
    float s = size_in[2 * i];
    for (int c = threadIdx.x; c < 1024; c += 256)
        xout[(size_t)tb * 1024 + c] = (x[(size_t)(2 * i) * 1024 + c] * s) / s;
}

__global__ __launch_bounds__(256) void dst6_kernel(const float* __restrict__ x,
                                                   const float* __restrict__ size_in,
                                                   const int* __restrict__ edgeidx,
                                                   const int* __restrict__ nidx,
                                                   float* __restrict__ xout,
                                                   int r, int out_off)
{
    int j = blockIdx.x;
    __shared__ int   list[64];
    __shared__ int   cnt_s;
    __shared__ float ns_s;
    if (threadIdx.x == 0) {
        int n = 0; float ns = size_in[2 * j + 1];
        for (int m = 0; m < r; ++m) {
            int i2 = edgeidx[m];
            if (nidx[i2] == j) { list[n++] = i2; ns += size_in[2 * i2]; }
        }
        cnt_s = n; ns_s = ns;
    }
    __syncthreads();
    int n = cnt_s; float ns = ns_s;
    float sodd = size_in[2 * j + 1];
    for (int c = threadIdx.x; c < 1024; c += 256) {
        float acc = x[(size_t)(2 * j + 1) * 1024 + c] * sodd;
        for (int u = 0; u < n; ++u) {
            int i2 = list[u];
            acc += x[(size_t)(2 * i2) * 1024 + c] * size_in[2 * i2];
        }
        xout[(size_t)(out_off + j) * 1024 + c] = acc / ns;
    }
}

// ---- bf16 cast / transpose-cast ------------------------------------------
__global__ __launch_bounds__(256) void castx_kernel(const float* __restrict__ in,
                                                    __hip_bfloat16* __restrict__ out, int n)
{
    int i = blockIdx.x * 256 + threadIdx.x;
    if (i < n) out[i] = __float2bfloat16(in[i]);
}

// in[K][N] fp32 -> outT[N][K] bf16 (32x32 LDS tile transpose)
__global__ __launch_bounds__(256) void transcast_kernel(const float* __restrict__ in,
                                                        __hip_bfloat16* __restrict__ outT,
                                                        int K, int N)
{
    __shared__ float tile[32][33];
    int n0 = blockIdx.x * 32, k0 = blockIdx.y * 32;
    int tx = threadIdx.x & 31, ty = threadIdx.x >> 5;
#pragma unroll
    for (int u = 0; u < 4; ++u) {
        int k = k0 + ty + u * 8;
        tile[ty + u * 8][tx] = in[(size_t)k * N + n0 + tx];
    }
    __syncthreads();
#pragma unroll
    for (int u = 0; u < 4; ++u) {
        int n = n0 + ty + u * 8;
        outT[(size_t)n * K + k0 + tx] = __float2bfloat16(tile[tx][ty + u * 8]);
    }
}

// ---- bf16 MFMA GEMM: C = act(A@B^T + bias) -------------------------------
// A[M][K] bf16, Bt[N][K] bf16. 64x64 tile, BK=64, 4 waves (2x2), each wave
// 32x32 (2x2 frags of 16x16x32). Staging via global_load_lds width-16:
// LDS stays lane-linear; the XOR swizzle (slot sc = cc ^ (row&7)) is applied
// by pre-swizzling the per-lane GLOBAL source chunk (cc = (c&7)^((c>>3)&7)),
// so the existing swizzled ds_read side is unchanged (G21 both-sides rule).
template <int ACT, int OUTBF16>
__global__ __launch_bounds__(256) void mfma_gemm_kernel(
    const unsigned short* __restrict__ A,
    const unsigned short* __restrict__ Bt,
    const float* __restrict__ bias,
    void* __restrict__ Cout, int M, int N, int K)
{
    __shared__ unsigned short As[64 * 64];
    __shared__ unsigned short Bs[64 * 64];
    const int t = threadIdx.x;
    const int lane = t & 63, wave = t >> 6;
    const int wm = wave >> 1, wn = wave & 1;
    const int bi = blockIdx.y * 64, bj = blockIdx.x * 64;
    const int l15 = lane & 15, lg = lane >> 4;

    f32x4 acc[2][2];
#pragma unroll
    for (int m = 0; m < 2; ++m)
#pragma unroll
        for (int n = 0; n < 2; ++n)
#pragma unroll
            for (int r = 0; r < 4; ++r) acc[m][n][r] = 0.f;

    for (int k0 = 0; k0 < K; k0 += 64) {
        __syncthreads();
#pragma unroll
        for (int q = 0; q < 2; ++q) {
            int c   = q * 256 + wave * 64 + lane;   // LDS-linear chunk id
            int row = c >> 3;
            int cc  = (c & 7) ^ (row & 7);          // pre-swizzled global chunk
            int ldsbase = (q * 256 + wave * 64) * 8; // shorts; wave-uniform
            __builtin_amdgcn_global_load_lds(
                (const void*)(A + (size_t)(bi + row) * K + k0 + cc * 8),
                (void*)&As[ldsbase], 16, 0, 0);
            __builtin_amdgcn_global_load_lds(
                (const void*)(Bt + (size_t)(bj + row) * K + k0 + cc * 8),
                (void*)&Bs[ldsbase], 16, 0, 0);
        }
        __syncthreads();
#pragma unroll
        for (int kc = 0; kc < 2; ++kc) {
            bf16x8 af[2], bfr[2];
#pragma unroll
            for (int m = 0; m < 2; ++m) {
                int row = wm * 32 + m * 16 + l15;
                int c = kc * 4 + lg;
                int sc = c ^ (row & 7);
                af[m] = *reinterpret_cast<const bf16x8*>(&As[row * 64 + sc * 8]);
            }
#pragma unroll
            for (int n = 0; n < 2; ++n) {
                int col = wn * 32 + n * 16 + l15;
                int c = kc * 4 + lg;
                int sc = c ^ (col & 7);
                bfr[n] = *reinterpret_cast<const bf16x8*>(&Bs[col * 64 + sc * 8]);
            }
#pragma unroll
            for (int m = 0; m < 2; ++m)
#pragma unroll
                for (int n = 0; n < 2; ++n)
                    acc[m][n] = __builtin_amdgcn_mfma_f32_16x16x32_bf16(
                        af[m], bfr[n], acc[m][n], 0, 0, 0);
        }
    }

#pragma unroll
    for (int m = 0; m < 2; ++m) {
#pragma unroll
        for (int n = 0; n < 2; ++n) {
            int gcol = bj + wn * 32 + n * 16 + l15;
            float bv = bias[gcol];
#pragma unroll
            for (int r = 0; r < 4; ++r) {
                int grow = bi + wm * 32 + m * 16 + lg * 4 + r;
                float v = acc[m][n][r] + bv;
                if (ACT) v = 0.5f * v * (1.0f + erff(v * 0.70710678118654752440f));
                if (OUTBF16)
                    ((__hip_bfloat16*)Cout)[(size_t)grow * N + gcol] = __float2bfloat16(v);
                else
                    ((float*)Cout)[(size_t)grow * N + gcol] = v;
            }
        }
    }
}

extern "C" void kernel_launch(void* const* d_in, const int* in_sizes, int n_in,
                              void* d_out, int out_size, void* d_ws, size_t ws_size,
                              hipStream_t stream)
{
    const float* x_in = (const float*)d_in[0];   // (18432,1024)
    const float* W1   = (const float*)d_in[1];   // (1024,4096)
    const float* b1   = (const float*)d_in[2];
    const float* W2   = (const float*)d_in[3];   // (4096,4096)
    const float* b2   = (const float*)d_in[4];
    float* out = (float*)d_out;                  // (512,4096) fp32

    // ---- workspace carve -----------------------------------------------------
    const size_t XBYTES = (size_t)9216 * 1024 * 4;   // 37.75 MB
    char* base = (char*)d_ws;
    float* xA     = (float*)base;
    float* xB     = (float*)(base + XBYTES);
    float* metric = (float*)(base + 2 * XBYTES);
    char*  tail   = base + 2 * XBYTES + (size_t)18432 * 64 * 4;
    float* sizeA  = (float*)tail;               tail += 9216 * 4;
    float* sizeB  = (float*)tail;               tail += 9216 * 4;
    float* nmax   = (float*)tail;               tail += 9216 * 4;
    int*   nidx   = (int*)tail;                 tail += 9216 * 4;
    int*   edgeidx= (int*)tail;                 tail += 2048;

    // bf16 overlays (live only after the merge rounds):
    __hip_bfloat16* W2t  = (__hip_bfloat16*)xA;
    __hip_bfloat16* h_bf = (__hip_bfloat16*)((char*)xB + (2u << 20));
    __hip_bfloat16* xbf  = (__hip_bfloat16*)((char*)xB + (6u << 20));
    __hip_bfloat16* W1t  = (__hip_bfloat16*)((char*)xB + (7u << 20));

    const int pcount[6] = {18432, 9216, 4608, 2304, 1152, 576};
    float* xbufs[2] = {xA, xB};
    float* sbufs[2] = {sizeA, sizeB};

    const float* xcur = x_in;
    const float* scur = nullptr;

    for (int rd = 0; rd < 6; ++rd) {
        int p  = pcount[rd];
        int P2 = p / 2;
        float* xout = xbufs[rd & 1];
        float* sout = sbufs[rd & 1];
        // pmax/pidx scratch in the region merge is ABOUT to overwrite (dead
        // before merge writes).
        float* pmax = xout;
        int*   pidx = (int*)((char*)xout + (16u << 20));

        metric_kernel<<<dim3((p + 3) / 4), dim3(256), 0, stream>>>(xcur, metric, p);

        int IB = (P2 + 63) / 64;
        int JB = (P2 + 127) / 128;
        scores_kernel<<<dim3(IB, JB), dim3(256), 0, stream>>>(metric, pmax, pidx, P2);
        reduce_kernel<<<dim3((P2 + 255) / 256), dim3(256), 0, stream>>>(
            pmax, pidx, nmax, nidx, P2, JB);

        if (rd < 5) {
            merge_kernel<<<dim3(P2 / JPB), dim3(256), 0, stream>>>(
                xcur, scur, nidx, nmax, xout, sout, P2);
        } else {
            rank_kernel<<<dim3(1), dim3(512), 0, stream>>>(nmax, edgeidx, P2);
            unm_kernel<<<dim3(P2 - 64), dim3(256), 0, stream>>>(xcur, scur, edgeidx,
                                                                xout, 64);
            dst6_kernel<<<dim3(P2), dim3(256), 0, stream>>>(xcur, scur, edgeidx, nidx,
                                                            xout, 64, P2 - 64);
        }
        xcur = xout;
        scur = sout;
    }

    // ---- bf16 casts ----------------------------------------------------------
    castx_kernel<<<dim3((512 * 1024 + 255) / 256), dim3(256), 0, stream>>>(
        xcur, xbf, 512 * 1024);
    transcast_kernel<<<dim3(4096 / 32, 1024 / 32), dim3(256), 0, stream>>>(
        W1, W1t, 1024, 4096);
    transcast_kernel<<<dim3(4096 / 32, 4096 / 32), dim3(256), 0, stream>>>(
        W2, W2t, 4096, 4096);

    // ---- MLP: h = gelu(x@W1+b1) [bf16]; out = h@W2+b2 [fp32] ----------------
    mfma_gemm_kernel<1, 1><<<dim3(4096 / 64, 512 / 64), dim3(256), 0, stream>>>(
        (const unsigned short*)xbf, (const unsigned short*)W1t, b1,
        (void*)h_bf, 512, 4096, 1024);
    mfma_gemm_kernel<0, 0><<<dim3(4096 / 64, 512 / 64), dim3(256), 0, stream>>>(
        (const unsigned short*)h_bf, (const unsigned short*)W2t, b2,
        (void*)out, 512, 4096, 4096);
}

// Round 5
// 794.414 us; speedup vs baseline: 1.2047x; 1.2047x over previous
//
#include <hip/hip_runtime.h>
#include <hip/hip_bf16.h>

// ---------------------------------------------------------------------------
// ToMe16 token merge (6 rounds, fp32, numpy-exact decision order) +
// bf16-MFMA 2-layer MLP.  MI355X gfx950.
// R5: merge/gemm reverted verbatim to R3 (885us build); scores redesigned:
// 64x128 tile + d-split halves (LDS 25.6KB -> 6 blk/CU) + conflict-free
// staging. FP chain per (i,j) unchanged (ascending d, scalar fmaf).
// ---------------------------------------------------------------------------

typedef __attribute__((ext_vector_type(8))) short bf16x8;
typedef __attribute__((ext_vector_type(4))) float f32x4;

// metric = mean over 16 heads of x (p,16,64), then L2-normalize rows.
__global__ __launch_bounds__(256) void metric_kernel(const float* __restrict__ x,
                                                     float* __restrict__ mnorm, int p)
{
    int row  = blockIdx.x * 4 + (threadIdx.x >> 6);
    int lane = threadIdx.x & 63;
    if (row >= p) return;
    const float* xr = x + (size_t)row * 1024;
    float m = 0.f;
#pragma unroll
    for (int h = 0; h < 16; ++h) m += xr[h * 64 + lane];
    m *= 0.0625f;
    float s = m * m;
#pragma unroll
    for (int off = 32; off > 0; off >>= 1) s += __shfl_xor(s, off, 64);
    mnorm[(size_t)row * 64 + lane] = m / sqrtf(s);
}

// scores[i][j] = dot(a_i, b_j), d=0..63 scalar fmaf ascending (bit-identical
// chain to the proven R2/R3 kernels => same argmax decisions).
// Tile i64 x j128; d staged in 2 halves of 32 (As[32][68], Bs[32][132] =
// 25.6KB -> 6 blocks/CU). Staging lanes span i/j (not d) => banks spread,
// <=2-way conflicts. Micro: per d, 3x b128 read + 32 fmaf per thread.
__global__ __launch_bounds__(256) void scores_kernel(const float* __restrict__ metric,
                                                     float* __restrict__ pmax,
                                                     int* __restrict__ pidx, int P2)
{
    __shared__ float As[32 * 68];
    __shared__ float Bs[32 * 132];
    const int t = threadIdx.x;
    const int i0 = blockIdx.x * 64, j0 = blockIdx.y * 128;
    const int tx = t & 15, ty = t >> 4;

    float acc[4][8];
#pragma unroll
    for (int u = 0; u < 4; ++u)
#pragma unroll
        for (int v = 0; v < 8; ++v) acc[u][v] = 0.f;

#pragma unroll
    for (int h = 0; h < 2; ++h) {
        const int dbase = 32 * h;
        if (h) __syncthreads();              // WAR on shared buffers
        // As: 64i x 32d, idx = i*16 + d16 + 1024*dhi  (lanes span i -> no conflict)
#pragma unroll
        for (int u = 0; u < 8; ++u) {
            int idx = u * 256 + t;
            int d16 = idx & 15, i = (idx >> 4) & 63, dhi = idx >> 10;
            int d = dhi * 16 + d16;
            int gi = i0 + i;
            As[d * 68 + i] = (gi < P2) ? metric[(size_t)(2 * gi) * 64 + dbase + d] : 0.f;
        }
        // Bs: 128j x 32d, idx = j*16 + d16 + 2048*dhi
#pragma unroll
        for (int u = 0; u < 16; ++u) {
            int idx = u * 256 + t;
            int d16 = idx & 15, j = (idx >> 4) & 127, dhi = idx >> 11;
            int d = dhi * 16 + d16;
            int gj = j0 + j;
            Bs[d * 132 + j] = (gj < P2) ? metric[(size_t)(2 * gj + 1) * 64 + dbase + d] : 0.f;
        }
        __syncthreads();
#pragma unroll 4
        for (int d = 0; d < 32; ++d) {
            float4 av = *reinterpret_cast<const float4*>(&As[d * 68 + ty * 4]);
            float4 b0 = *reinterpret_cast<const float4*>(&Bs[d * 132 + tx * 4]);
            float4 b1 = *reinterpret_cast<const float4*>(&Bs[d * 132 + 64 + tx * 4]);
            float a_[4] = {av.x, av.y, av.z, av.w};
            float b_[8] = {b0.x, b0.y, b0.z, b0.w, b1.x, b1.y, b1.z, b1.w};
#pragma unroll
            for (int u = 0; u < 4; ++u)
#pragma unroll
                for (int v = 0; v < 8; ++v)
                    acc[u][v] = fmaf(a_[u], b_[v], acc[u][v]);
        }
    }

#pragma unroll
    for (int u = 0; u < 4; ++u) {
        float best = -3.0e38f; int bj = 0x7fffffff;
        // ascending j within thread: group0 (tx*4+v), then group1 (64+tx*4+v)
#pragma unroll
        for (int v = 0; v < 4; ++v) {
            int j = j0 + tx * 4 + v;
            if (j < P2 && acc[u][v] > best) { best = acc[u][v]; bj = j; }
        }
#pragma unroll
        for (int v = 0; v < 4; ++v) {
            int j = j0 + 64 + tx * 4 + v;
            if (j < P2 && acc[u][4 + v] > best) { best = acc[u][4 + v]; bj = j; }
        }
#pragma unroll
        for (int off = 1; off < 16; off <<= 1) {
            float ob = __shfl_xor(best, off, 64);
            int   oj = __shfl_xor(bj,   off, 64);
            if (ob > best || (ob == best && oj < bj)) { best = ob; bj = oj; }
        }
        if (tx == 0) {
            int gi = i0 + ty * 4 + u;
            if (gi < P2) {
                pmax[(size_t)blockIdx.y * P2 + gi] = best;
                pidx[(size_t)blockIdx.y * P2 + gi] = bj;
            }
        }
    }
}

__global__ __launch_bounds__(256) void reduce_kernel(const float* __restrict__ pmax,
                                                     const int* __restrict__ pidx,
                                                     float* __restrict__ nmax,
                                                     int* __restrict__ nidx,
                                                     int P2, int JS)
{
    int i = blockIdx.x * 256 + threadIdx.x;
    if (i >= P2) return;
    float best = -3.3e38f; int bj = 0;
    for (int js = 0; js < JS; ++js) {
        float v = pmax[(size_t)js * P2 + i];
        if (v > best) { best = v; bj = pidx[(size_t)js * P2 + i]; }
    }
    nmax[i] = best; nidx[i] = bj;
}

// Rounds 1-5 (r == p/2). Duplicate accumulation ordered by (node_max desc,
// idx asc) == np.add.at's source order.   [verbatim R3]
__global__ __launch_bounds__(256) void merge_kernel(const float* __restrict__ x,
                                                    const float* __restrict__ size_in,
                                                    const int* __restrict__ nidx,
                                                    const float* __restrict__ nmax,
                                                    float* __restrict__ xout,
                                                    float* __restrict__ size_out, int P2)
{
    int j = blockIdx.x;
    __shared__ int   list[128];
    __shared__ int   cnt_s;
    __shared__ float ns_s;
    if (threadIdx.x == 0) cnt_s = 0;
    __syncthreads();
    for (int i = threadIdx.x; i < P2; i += 256) {
        if (nidx[i] == j) { int p = atomicAdd(&cnt_s, 1); if (p < 128) list[p] = i; }
    }
    __syncthreads();
    int total = cnt_s;
    bool over = (total > 128);
    if (threadIdx.x == 0) {
        float ns = size_in ? size_in[2 * j + 1] : 1.0f;
        if (!over) {
            for (int u = 1; u < total; ++u) {
                int v = list[u]; float kv = nmax[v]; int w = u - 1;
                while (w >= 0) {
                    int lw = list[w]; float kw = nmax[lw];
                    if (kw < kv || (kw == kv && lw > v)) { list[w + 1] = lw; --w; }
                    else break;
                }
                list[w + 1] = v;
            }
            for (int u = 0; u < total; ++u) ns += size_in ? size_in[2 * list[u]] : 1.0f;
        } else {
            for (int i = 0; i < P2; ++i)
                if (nidx[i] == j) ns += size_in ? size_in[2 * i] : 1.0f;
        }
        ns_s = ns;
        size_out[j] = ns;
    }
    __syncthreads();
    float ns   = ns_s;
    float sodd = size_in ? size_in[2 * j + 1] : 1.0f;
    for (int c = threadIdx.x; c < 1024; c += 256) {
        float acc = x[(size_t)(2 * j + 1) * 1024 + c] * sodd;
        if (!over) {
            for (int u = 0; u < total; ++u) {
                int i2 = list[u];
                float si = size_in ? size_in[2 * i2] : 1.0f;
                acc += x[(size_t)(2 * i2) * 1024 + c] * si;
            }
        } else {
            for (int i2 = 0; i2 < P2; ++i2) {
                if (nidx[i2] == j) {
                    float si = size_in ? size_in[2 * i2] : 1.0f;
                    acc += x[(size_t)(2 * i2) * 1024 + c] * si;
                }
            }
        }
        xout[(size_t)j * 1024 + c] = acc / ns;
    }
}

// Round 6 helpers (stable descending argsort, unm gather, dst scatter).
__global__ __launch_bounds__(512) void rank_kernel(const float* __restrict__ nmax,
                                                   int* __restrict__ edgeidx, int n)
{
    int i = threadIdx.x;
    if (i >= n) return;
    float v = nmax[i];
    int r = 0;
    for (int k = 0; k < n; ++k) {
        float u = nmax[k];
        if (u > v || (u == v && k < i)) ++r;
    }
    edgeidx[r] = i;
}

__global__ __launch_bounds__(256) void unm_kernel(const float* __restrict__ x,
                                                  const float* __restrict__ size_in,
                                                  const int* __restrict__ edgeidx,
                                                  float* __restrict__ xout, int r)
{
    int tb = blockIdx.x;
    int i = edgeidx[r + tb];
    float s = size_in[2 * i];
    for (int c = threadIdx.x; c < 1024; c += 256)
        xout[(size_t)tb * 1024 + c] = (x[(size_t)(2 * i) * 1024 + c] * s) / s;
}

__global__ __launch_bounds__(256) void dst6_kernel(const float* __restrict__ x,
                                                   const float* __restrict__ size_in,
                                                   const int* __restrict__ edgeidx,
                                                   const int* __restrict__ nidx,
                                                   float* __restrict__ xout,
                                                   int r, int out_off)
{
    int j = blockIdx.x;
    __shared__ int   list[64];
    __shared__ int   cnt_s;
    __shared__ float ns_s;
    if (threadIdx.x == 0) {
        int n = 0; float ns = size_in[2 * j + 1];
        for (int m = 0; m < r; ++m) {
            int i2 = edgeidx[m];
            if (nidx[i2] == j) { list[n++] = i2; ns += size_in[2 * i2]; }
        }
        cnt_s = n; ns_s = ns;
    }
    __syncthreads();
    int n = cnt_s; float ns = ns_s;
    float sodd = size_in[2 * j + 1];
    for (int c = threadIdx.x; c < 1024; c += 256) {
        float acc = x[(size_t)(2 * j + 1) * 1024 + c] * sodd;
        for (int u = 0; u < n; ++u) {
            int i2 = list[u];
            acc += x[(size_t)(2 * i2) * 1024 + c] * size_in[2 * i2];
        }
        xout[(size_t)(out_off + j) * 1024 + c] = acc / ns;
    }
}

// ---- bf16 cast / transpose-cast ------------------------------------------
__global__ __launch_bounds__(256) void castx_kernel(const float* __restrict__ in,
                                                    __hip_bfloat16* __restrict__ out, int n)
{
    int i = blockIdx.x * 256 + threadIdx.x;
    if (i < n) out[i] = __float2bfloat16(in[i]);
}

// in[K][N] fp32 -> outT[N][K] bf16 (32x32 LDS tile transpose)
__global__ __launch_bounds__(256) void transcast_kernel(const float* __restrict__ in,
                                                        __hip_bfloat16* __restrict__ outT,
                                                        int K, int N)
{
    __shared__ float tile[32][33];
    int n0 = blockIdx.x * 32, k0 = blockIdx.y * 32;
    int tx = threadIdx.x & 31, ty = threadIdx.x >> 5;
#pragma unroll
    for (int u = 0; u < 4; ++u) {
        int k = k0 + ty + u * 8;
        tile[ty + u * 8][tx] = in[(size_t)k * N + n0 + tx];
    }
    __syncthreads();
#pragma unroll
    for (int u = 0; u < 4; ++u) {
        int n = n0 + ty + u * 8;
        outT[(size_t)n * K + k0 + tx] = __float2bfloat16(tile[tx][ty + u * 8]);
    }
}

// ---- bf16 MFMA GEMM: C = act(A@B^T + bias)  [verbatim R3] ----------------
template <int ACT, int OUTBF16>
__global__ __launch_bounds__(256) void mfma_gemm_kernel(
    const unsigned short* __restrict__ A,
    const unsigned short* __restrict__ Bt,
    const float* __restrict__ bias,
    void* __restrict__ Cout, int M, int N, int K)
{
    __shared__ unsigned short As[64 * 64];
    __shared__ unsigned short Bs[64 * 64];
    const int t = threadIdx.x;
    const int lane = t & 63, wave = t >> 6;
    const int wm = wave >> 1, wn = wave & 1;
    const int bi = blockIdx.y * 64, bj = blockIdx.x * 64;
    const int l15 = lane & 15, lg = lane >> 4;

    f32x4 acc[2][2];
#pragma unroll
    for (int m = 0; m < 2; ++m)
#pragma unroll
        for (int n = 0; n < 2; ++n)
#pragma unroll
            for (int r = 0; r < 4; ++r) acc[m][n][r] = 0.f;

    for (int k0 = 0; k0 < K; k0 += 64) {
        __syncthreads();
#pragma unroll
        for (int q = 0; q < 2; ++q) {
            int c = q * 256 + t;          // 16B chunk id, 512 per tile
            int row = c >> 3, cc = c & 7;
            int sc = cc ^ (row & 7);      // swizzle applied on the LDS slot
            *reinterpret_cast<int4*>(&As[row * 64 + sc * 8]) =
                *reinterpret_cast<const int4*>(A + (size_t)(bi + row) * K + k0 + cc * 8);
            *reinterpret_cast<int4*>(&Bs[row * 64 + sc * 8]) =
                *reinterpret_cast<const int4*>(Bt + (size_t)(bj + row) * K + k0 + cc * 8);
        }
        __syncthreads();
#pragma unroll
        for (int kc = 0; kc < 2; ++kc) {
            bf16x8 af[2], bfr[2];
#pragma unroll
            for (int m = 0; m < 2; ++m) {
                int row = wm * 32 + m * 16 + l15;
                int c = kc * 4 + lg;
                int sc = c ^ (row & 7);
                af[m] = *reinterpret_cast<const bf16x8*>(&As[row * 64 + sc * 8]);
            }
#pragma unroll
            for (int n = 0; n < 2; ++n) {
                int col = wn * 32 + n * 16 + l15;
                int c = kc * 4 + lg;
                int sc = c ^ (col & 7);
                bfr[n] = *reinterpret_cast<const bf16x8*>(&Bs[col * 64 + sc * 8]);
            }
#pragma unroll
            for (int m = 0; m < 2; ++m)
#pragma unroll
                for (int n = 0; n < 2; ++n)
                    acc[m][n] = __builtin_amdgcn_mfma_f32_16x16x32_bf16(
                        af[m], bfr[n], acc[m][n], 0, 0, 0);
        }
    }

#pragma unroll
    for (int m = 0; m < 2; ++m) {
#pragma unroll
        for (int n = 0; n < 2; ++n) {
            int gcol = bj + wn * 32 + n * 16 + l15;
            float bv = bias[gcol];
#pragma unroll
            for (int r = 0; r < 4; ++r) {
                int grow = bi + wm * 32 + m * 16 + lg * 4 + r;
                float v = acc[m][n][r] + bv;
                if (ACT) v = 0.5f * v * (1.0f + erff(v * 0.70710678118654752440f));
                if (OUTBF16)
                    ((__hip_bfloat16*)Cout)[(size_t)grow * N + gcol] = __float2bfloat16(v);
                else
                    ((float*)Cout)[(size_t)grow * N + gcol] = v;
            }
        }
    }
}

extern "C" void kernel_launch(void* const* d_in, const int* in_sizes, int n_in,
                              void* d_out, int out_size, void* d_ws, size_t ws_size,
                              hipStream_t stream)
{
    const float* x_in = (const float*)d_in[0];   // (18432,1024)
    const float* W1   = (const float*)d_in[1];   // (1024,4096)
    const float* b1   = (const float*)d_in[2];
    const float* W2   = (const float*)d_in[3];   // (4096,4096)
    const float* b2   = (const float*)d_in[4];
    float* out = (float*)d_out;                  // (512,4096) fp32

    // ---- workspace carve -----------------------------------------------------
    const size_t XBYTES = (size_t)9216 * 1024 * 4;   // 37.75 MB
    char* base = (char*)d_ws;
    float* xA     = (float*)base;
    float* xB     = (float*)(base + XBYTES);
    float* metric = (float*)(base + 2 * XBYTES);
    char*  tail   = base + 2 * XBYTES + (size_t)18432 * 64 * 4;
    float* sizeA  = (float*)tail;               tail += 9216 * 4;
    float* sizeB  = (float*)tail;               tail += 9216 * 4;
    float* nmax   = (float*)tail;               tail += 9216 * 4;
    int*   nidx   = (int*)tail;                 tail += 9216 * 4;
    int*   edgeidx= (int*)tail;                 tail += 2048;

    // bf16 overlays (live only after the merge rounds):
    __hip_bfloat16* W2t  = (__hip_bfloat16*)xA;
    __hip_bfloat16* h_bf = (__hip_bfloat16*)((char*)xB + (2u << 20));
    __hip_bfloat16* xbf  = (__hip_bfloat16*)((char*)xB + (6u << 20));
    __hip_bfloat16* W1t  = (__hip_bfloat16*)((char*)xB + (7u << 20));

    const int pcount[6] = {18432, 9216, 4608, 2304, 1152, 576};
    float* xbufs[2] = {xA, xB};
    float* sbufs[2] = {sizeA, sizeB};

    const float* xcur = x_in;
    const float* scur = nullptr;

    for (int rd = 0; rd < 6; ++rd) {
        int p  = pcount[rd];
        int P2 = p / 2;
        float* xout = xbufs[rd & 1];
        float* sout = sbufs[rd & 1];
        // pmax/pidx scratch in the region merge is ABOUT to overwrite (dead
        // before merge writes).
        float* pmax = xout;
        int*   pidx = (int*)((char*)xout + (16u << 20));

        metric_kernel<<<dim3((p + 3) / 4), dim3(256), 0, stream>>>(xcur, metric, p);

        int IB = (P2 + 63) / 64;
        int JB = (P2 + 127) / 128;
        scores_kernel<<<dim3(IB, JB), dim3(256), 0, stream>>>(metric, pmax, pidx, P2);
        reduce_kernel<<<dim3((P2 + 255) / 256), dim3(256), 0, stream>>>(
            pmax, pidx, nmax, nidx, P2, JB);

        if (rd < 5) {
            merge_kernel<<<dim3(P2), dim3(256), 0, stream>>>(xcur, scur, nidx, nmax,
                                                             xout, sout, P2);
        } else {
            rank_kernel<<<dim3(1), dim3(512), 0, stream>>>(nmax, edgeidx, P2);
            unm_kernel<<<dim3(P2 - 64), dim3(256), 0, stream>>>(xcur, scur, edgeidx,
                                                                xout, 64);
            dst6_kernel<<<dim3(P2), dim3(256), 0, stream>>>(xcur, scur, edgeidx, nidx,
                                                            xout, 64, P2 - 64);
        }
        xcur = xout;
        scur = sout;
    }

    // ---- bf16 casts ----------------------------------------------------------
    castx_kernel<<<dim3((512 * 1024 + 255) / 256), dim3(256), 0, stream>>>(
        xcur, xbf, 512 * 1024);
    transcast_kernel<<<dim3(4096 / 32, 1024 / 32), dim3(256), 0, stream>>>(
        W1, W1t, 1024, 4096);
    transcast_kernel<<<dim3(4096 / 32, 4096 / 32), dim3(256), 0, stream>>>(
        W2, W2t, 4096, 4096);

    // ---- MLP: h = gelu(x@W1+b1) [bf16]; out = h@W2+b2 [fp32] ----------------
    mfma_gemm_kernel<1, 1><<<dim3(4096 / 64, 512 / 64), dim3(256), 0, stream>>>(
        (const unsigned short*)xbf, (const unsigned short*)W1t, b1,
        (void*)h_bf, 512, 4096, 1024);
    mfma_gemm_kernel<0, 0><<<dim3(4096 / 64, 512 / 64), dim3(256), 0, stream>>>(
        (const unsigned short*)h_bf, (const unsigned short*)W2t, b2,
        (void*)out, 512, 4096, 4096);
}